// Round 1
// baseline (4995.165 us; speedup 1.0000x reference)
//
#include <hip/hip_runtime.h>
#include <math.h>

// Round 0: correct f32 baseline.
// Pipeline:
//  1) q  = query @ Wq.T + bq              [8192, 4096]
//  2) vp = value @ Wv.T + bv              [8192, 2048]
//  3) scores^T[bh][e][t] = (1/sqrt(512)) * sum_s q[b,t,h*512+s] * key[b,s,h*256+e]
//  4) softmax over t (contiguous) with mask[b,t]
//  5) x[b][e][h][vv] = sum_t attn[bh][e][t] * vp[b,t,h*256+vv]
//  6) out = x2 @ Wo.T + bo                [4096, 2048]
// All f32 vector compute (no fp32 MFMA on CDNA4). Baseline for later bf16-MFMA rounds.

constexpr int Bn = 16, T = 512, DQ = 4096, DK = 2048, H = 8;
constexpr int dq = DQ / H;   // 512
constexpr int dk = DK / H;   // 256

// ---------------------------------------------------------------------------
// GEMM NT + bias: C[m,n] = sum_k A[m,k] * B[n,k] + bias[n]
// A: [M,K] row-major, B: [N,K] row-major. BM=BN=128, BK=16, 256 thr, 8x8/thr.
// ---------------------------------------------------------------------------
__global__ __launch_bounds__(256) void gemm_nt_bias(
    const float* __restrict__ A, const float* __restrict__ B,
    const float* __restrict__ bias, float* __restrict__ C,
    int M, int N, int K)
{
    constexpr int BM = 128, BN = 128, BK = 16;
    __shared__ float As[BK][BM + 4];
    __shared__ float Bs[BK][BN + 4];
    const int tid = threadIdx.x;
    const int bm = blockIdx.y * BM;
    const int bn = blockIdx.x * BN;
    const int tx = tid & 15, ty = tid >> 4;

    float acc[8][8];
#pragma unroll
    for (int i = 0; i < 8; ++i)
#pragma unroll
        for (int j = 0; j < 8; ++j) acc[i][j] = 0.f;

    for (int k0 = 0; k0 < K; k0 += BK) {
#pragma unroll
        for (int it = 0; it < 2; ++it) {
            int jj  = tid + it * 256;     // 0..511 (512 float4 per 128x16 tile)
            int row = jj >> 2;            // 0..127
            int c4  = (jj & 3) * 4;       // 0,4,8,12
            float4 va = *reinterpret_cast<const float4*>(&A[(size_t)(bm + row) * K + k0 + c4]);
            As[c4 + 0][row] = va.x; As[c4 + 1][row] = va.y;
            As[c4 + 2][row] = va.z; As[c4 + 3][row] = va.w;
            float4 vb = *reinterpret_cast<const float4*>(&B[(size_t)(bn + row) * K + k0 + c4]);
            Bs[c4 + 0][row] = vb.x; Bs[c4 + 1][row] = vb.y;
            Bs[c4 + 2][row] = vb.z; Bs[c4 + 3][row] = vb.w;
        }
        __syncthreads();
#pragma unroll
        for (int kk = 0; kk < BK; ++kk) {
            float4 a0 = *reinterpret_cast<const float4*>(&As[kk][ty * 8]);
            float4 a1 = *reinterpret_cast<const float4*>(&As[kk][ty * 8 + 4]);
            float4 b0 = *reinterpret_cast<const float4*>(&Bs[kk][tx * 8]);
            float4 b1 = *reinterpret_cast<const float4*>(&Bs[kk][tx * 8 + 4]);
            float a[8] = {a0.x, a0.y, a0.z, a0.w, a1.x, a1.y, a1.z, a1.w};
            float b[8] = {b0.x, b0.y, b0.z, b0.w, b1.x, b1.y, b1.z, b1.w};
#pragma unroll
            for (int i = 0; i < 8; ++i)
#pragma unroll
                for (int j = 0; j < 8; ++j) acc[i][j] += a[i] * b[j];
        }
        __syncthreads();
    }

#pragma unroll
    for (int i = 0; i < 8; ++i) {
        int m = bm + ty * 8 + i;
#pragma unroll
        for (int j = 0; j < 8; j += 4) {
            int n = bn + tx * 8 + j;
            float4 o;
            o.x = acc[i][j + 0] + bias[n + 0];
            o.y = acc[i][j + 1] + bias[n + 1];
            o.z = acc[i][j + 2] + bias[n + 2];
            o.w = acc[i][j + 3] + bias[n + 3];
            *reinterpret_cast<float4*>(&C[(size_t)m * N + n]) = o;
        }
    }
}

// ---------------------------------------------------------------------------
// scores: per (b,h) slice, S^T[e][t] = scale * sum_s q[t,s] * key[s,e]
// q slice: lda=4096 (s contiguous). key slice: ldb=2048 (e contiguous).
// Tile 64x64 (M=t, N=e), BK=16, 256 thr, 4x4/thr. Output transposed store.
// ---------------------------------------------------------------------------
__global__ __launch_bounds__(256) void scores_kernel(
    const float* __restrict__ Q,    // [B, T, 4096]
    const float* __restrict__ Key,  // [B, T, 2048]
    float* __restrict__ S)          // [B*H, 256, 512]
{
    constexpr int BM = 64, BN = 64, BK = 16;
    const float scale = 0.044194173824159216f;  // 1/sqrt(512)
    const int bh = blockIdx.z, b = bh >> 3, h = bh & 7;
    const float* A  = Q   + (size_t)b * T * DQ + (size_t)h * dq;  // A[t,s], lda=4096
    const float* Bk = Key + (size_t)b * T * DK + (size_t)h * dk;  // B[s,e], ldb=2048
    float* out = S + (size_t)bh * dk * T;

    __shared__ float As[BK][BM + 4];  // [s][t]
    __shared__ float Bs[BK][BN + 4];  // [s][e]
    const int tid = threadIdx.x;
    const int tx = tid & 15, ty = tid >> 4;
    const int bm = blockIdx.y * BM, bn = blockIdx.x * BN;

    float acc[4][4];
#pragma unroll
    for (int i = 0; i < 4; ++i)
#pragma unroll
        for (int j = 0; j < 4; ++j) acc[i][j] = 0.f;

    for (int k0 = 0; k0 < dq; k0 += BK) {
        {   // A tile 64(t) x 16(s): 256 float4, 1/thread
            int row = tid >> 2;
            int c4  = (tid & 3) * 4;
            float4 va = *reinterpret_cast<const float4*>(&A[(size_t)(bm + row) * DQ + k0 + c4]);
            As[c4 + 0][row] = va.x; As[c4 + 1][row] = va.y;
            As[c4 + 2][row] = va.z; As[c4 + 3][row] = va.w;
        }
        {   // B tile 16(s) x 64(e): 256 float4, row-contiguous
            int row = tid >> 4;
            int c4  = (tid & 15) * 4;
            float4 vb = *reinterpret_cast<const float4*>(&Bk[(size_t)(k0 + row) * DK + bn + c4]);
            *reinterpret_cast<float4*>(&Bs[row][c4]) = vb;
        }
        __syncthreads();
#pragma unroll
        for (int kk = 0; kk < BK; ++kk) {
            float4 a = *reinterpret_cast<const float4*>(&As[kk][ty * 4]);
            float4 bb = *reinterpret_cast<const float4*>(&Bs[kk][tx * 4]);
            float av[4] = {a.x, a.y, a.z, a.w};
            float bv[4] = {bb.x, bb.y, bb.z, bb.w};
#pragma unroll
            for (int i = 0; i < 4; ++i)
#pragma unroll
                for (int j = 0; j < 4; ++j) acc[i][j] += av[i] * bv[j];
        }
        __syncthreads();
    }
    // transposed store: out[e][t], 4 consecutive t per thread -> float4
#pragma unroll
    for (int j = 0; j < 4; ++j) {
        int e = bn + tx * 4 + j;
        float4 o;
        o.x = acc[0][j] * scale; o.y = acc[1][j] * scale;
        o.z = acc[2][j] * scale; o.w = acc[3][j] * scale;
        *reinterpret_cast<float4*>(&out[(size_t)e * T + bm + ty * 4]) = o;
    }
}

// ---------------------------------------------------------------------------
// masked softmax over t (row-contiguous). One block (256 thr) per row of 512.
// ---------------------------------------------------------------------------
__global__ __launch_bounds__(256) void softmax_mask_kernel(
    float* __restrict__ S,            // [B*H, 256, 512] in/out
    const int* __restrict__ mask)     // [B, 1, 512]
{
    const int row = blockIdx.x;           // 0..32767
    const int b = row >> 11;              // row / (H*dk)
    float* p = S + (size_t)row * T;
    const int* mk = mask + (size_t)b * T;
    const int t0 = threadIdx.x;

    float v0 = mk[t0]       ? p[t0]       : -INFINITY;
    float v1 = mk[t0 + 256] ? p[t0 + 256] : -INFINITY;

    __shared__ float sm[4], ss[4];
    const int lane = threadIdx.x & 63, wid = threadIdx.x >> 6;

    float m = fmaxf(v0, v1);
#pragma unroll
    for (int o = 32; o > 0; o >>= 1) m = fmaxf(m, __shfl_down(m, o, 64));
    if (lane == 0) sm[wid] = m;
    __syncthreads();
    const float mx = fmaxf(fmaxf(sm[0], sm[1]), fmaxf(sm[2], sm[3]));

    float e0 = __expf(v0 - mx), e1 = __expf(v1 - mx);  // exp(-inf)=0 for masked
    float s = e0 + e1;
#pragma unroll
    for (int o = 32; o > 0; o >>= 1) s += __shfl_down(s, o, 64);
    if (lane == 0) ss[wid] = s;
    __syncthreads();
    const float inv = 1.0f / (ss[0] + ss[1] + ss[2] + ss[3]);

    p[t0]       = e0 * inv;
    p[t0 + 256] = e1 * inv;
}

// ---------------------------------------------------------------------------
// PV: per (b,h), x[e][vv] = sum_t attn[e,t] * vp[b,t,h*256+vv]
// Stored as X[b][e][h][vv] so the final GEMM sees row-major [4096, 2048].
// ---------------------------------------------------------------------------
__global__ __launch_bounds__(256) void pv_kernel(
    const float* __restrict__ Attn,  // [B*H, 256, 512]
    const float* __restrict__ Vp,    // [B, T, 2048]
    float* __restrict__ X)           // [B, 256, H, 256]
{
    constexpr int BM = 64, BN = 64, BK = 16;
    const int bh = blockIdx.z, b = bh >> 3, h = bh & 7;
    const float* A  = Attn + (size_t)bh * dk * T;                 // A[e,t], lda=512
    const float* Bv = Vp + (size_t)b * T * DK + (size_t)h * dk;   // B[t,vv], ldb=2048

    __shared__ float As[BK][BM + 4];  // [t][e]
    __shared__ float Bs[BK][BN + 4];  // [t][vv]
    const int tid = threadIdx.x;
    const int tx = tid & 15, ty = tid >> 4;
    const int bm = blockIdx.y * BM, bn = blockIdx.x * BN;

    float acc[4][4];
#pragma unroll
    for (int i = 0; i < 4; ++i)
#pragma unroll
        for (int j = 0; j < 4; ++j) acc[i][j] = 0.f;

    for (int k0 = 0; k0 < T; k0 += BK) {
        {
            int row = tid >> 2;
            int c4  = (tid & 3) * 4;
            float4 va = *reinterpret_cast<const float4*>(&A[(size_t)(bm + row) * T + k0 + c4]);
            As[c4 + 0][row] = va.x; As[c4 + 1][row] = va.y;
            As[c4 + 2][row] = va.z; As[c4 + 3][row] = va.w;
        }
        {
            int row = tid >> 4;
            int c4  = (tid & 15) * 4;
            float4 vb = *reinterpret_cast<const float4*>(&Bv[(size_t)(k0 + row) * DK + bn + c4]);
            *reinterpret_cast<float4*>(&Bs[row][c4]) = vb;
        }
        __syncthreads();
#pragma unroll
        for (int kk = 0; kk < BK; ++kk) {
            float4 a = *reinterpret_cast<const float4*>(&As[kk][ty * 4]);
            float4 bb = *reinterpret_cast<const float4*>(&Bs[kk][tx * 4]);
            float av[4] = {a.x, a.y, a.z, a.w};
            float bv[4] = {bb.x, bb.y, bb.z, bb.w};
#pragma unroll
            for (int i = 0; i < 4; ++i)
#pragma unroll
                for (int j = 0; j < 4; ++j) acc[i][j] += av[i] * bv[j];
        }
        __syncthreads();
    }
#pragma unroll
    for (int i = 0; i < 4; ++i) {
        int e = bm + ty * 4 + i;
        float4 o = {acc[i][0], acc[i][1], acc[i][2], acc[i][3]};
        *reinterpret_cast<float4*>(&X[(((size_t)b * dk + e) * H + h) * dk + bn + tx * 4]) = o;
    }
}

// ---------------------------------------------------------------------------
extern "C" void kernel_launch(void* const* d_in, const int* in_sizes, int n_in,
                              void* d_out, int out_size, void* d_ws, size_t ws_size,
                              hipStream_t stream)
{
    const float* query = (const float*)d_in[0];  // [16, 512, 4096]
    const float* key   = (const float*)d_in[1];  // [16, 512, 2048]
    const float* value = (const float*)d_in[2];  // [16, 512, 2048]
    const int*   mask  = (const int*)  d_in[3];  // [16, 1, 512]
    const float* Wq    = (const float*)d_in[4];  // [4096, 4096]
    const float* bq    = (const float*)d_in[5];  // [4096]
    const float* Wv    = (const float*)d_in[6];  // [2048, 2048]
    const float* bv    = (const float*)d_in[7];  // [2048]
    const float* Wo    = (const float*)d_in[8];  // [2048, 2048]
    const float* bo    = (const float*)d_in[9];  // [2048]
    float* out = (float*)d_out;                  // [16, 256, 2048]

    // workspace layout (floats): q 33.5M | vp 16.8M | scores 16.8M | x 8.4M  (~302 MB)
    float* q  = (float*)d_ws;
    float* vp = q  + (size_t)Bn * T * DQ;        // 33,554,432
    float* sc = vp + (size_t)Bn * T * DK;        // +16,777,216
    float* x  = sc + (size_t)Bn * H * dk * T;    // +16,777,216

    // 1) q = query @ Wq.T + bq    [8192, 4096]
    gemm_nt_bias<<<dim3(DQ / 128, (Bn * T) / 128), 256, 0, stream>>>(
        query, Wq, bq, q, Bn * T, DQ, DQ);
    // 2) vp = value @ Wv.T + bv   [8192, 2048]
    gemm_nt_bias<<<dim3(DK / 128, (Bn * T) / 128), 256, 0, stream>>>(
        value, Wv, bv, vp, Bn * T, DK, DK);
    // 3) scores^T per (b,h)
    scores_kernel<<<dim3(dk / 64, T / 64, Bn * H), 256, 0, stream>>>(q, key, sc);
    // 4) masked softmax over t
    softmax_mask_kernel<<<Bn * H * dk, 256, 0, stream>>>(sc, mask);
    // 5) PV per (b,h)
    pv_kernel<<<dim3(dk / 64, dk / 64, Bn * H), 256, 0, stream>>>(sc, vp, x);
    // 6) out = x2 @ Wo.T + bo     [4096, 2048]
    gemm_nt_bias<<<dim3(DK / 128, (Bn * dk) / 128), 256, 0, stream>>>(
        x, Wo, bo, out, Bn * dk, DK, DK);
}